// Round 4
// baseline (574.018 us; speedup 1.0000x reference)
//
#include <hip/hip_runtime.h>
#include <hip/hip_bf16.h>

// ---------------- problem constants ----------------
#define CC 192
#define NHEADS 6
#define HDIM 32
#define NTOK 49
#define NWIN 2048
#define MTOK 100352      // NWIN * NTOK
#define HIDDEN 768

typedef __hip_bfloat16 bf16;
typedef __attribute__((ext_vector_type(8))) short short8;
typedef __attribute__((ext_vector_type(4))) float f32x4;

// ---------------- weight fp32 -> bf16 conversion ----------------
__global__ __launch_bounds__(256) void k_wconv(
    const float* __restrict__ qw, const float* __restrict__ pw,
    const float* __restrict__ f1, const float* __restrict__ f2,
    bf16* __restrict__ o) {
  int i = blockIdx.x * 256 + threadIdx.x;
  if (i < 110592) o[i] = __float2bfloat16(qw[i]);
  else if (i < 147456) o[i] = __float2bfloat16(pw[i - 110592]);
  else if (i < 294912) o[i] = __float2bfloat16(f1[i - 147456]);
  else if (i < 442368) o[i] = __float2bfloat16(f2[i - 294912]);
}

// ---------------- bias6[h][49][49] = table[ridx[r*49+c]*6+h] -------------
__global__ __launch_bounds__(256) void k_bias(
    const float* __restrict__ table, const int* __restrict__ ridx,
    float* __restrict__ bias6) {
  int i = blockIdx.x * 256 + threadIdx.x;
  if (i >= 6 * 2401) return;
  int h = i / 2401, e = i - h * 2401;
  bias6[i] = table[ridx[e] * NHEADS + h];
}

// ---------------- A-register-resident MFMA GEMM ----------------
// MODE 0: A = x fp32, fused LN1 + roll(-3,-3) + window partition; bf16 out
// MODE 1: A = ao bf16; proj + window-reverse/roll + residual (fp32 scatter)
template <int MODE, int NT, int KC, int MF>
__global__ __launch_bounds__(256) void k_gemm_areg(
    const void* __restrict__ Ap, const bf16* __restrict__ W,
    const float* __restrict__ bias, void* __restrict__ out0,
    const void* __restrict__ aux, const float* __restrict__ lng,
    const float* __restrict__ lnb) {
  constexpr int K = KC * 192;
  constexpr int N = NT * 64;
  __shared__ bf16 Bs[2][64 * 192];   // 2 x 24 KB
  const int tid = threadIdx.x;
  const int wave = tid >> 6, lane = tid & 63;
  const int grp = lane >> 4, rA = lane & 15;
  const int cq = grp, cn = rA;
  const int m0 = blockIdx.x * (MF * 64);
  const int mrow = m0 + wave * (MF * 16);

  // ---- A fragments: global -> regs, exactly once ----
  short8 areg[MF][KC * 6];
  if constexpr (MODE == 1) {
#pragma unroll
    for (int mt = 0; mt < MF; ++mt) {
      const bf16* arow =
          (const bf16*)Ap + (size_t)(mrow + mt * 16 + rA) * K + grp * 8;
#pragma unroll
      for (int kt = 0; kt < KC * 6; ++kt)
        areg[mt][kt] = *(const short8*)(arow + kt * 32);
    }
  } else {
    // fp32 input + fused LayerNorm + roll/partition (K == 192).
#pragma unroll
    for (int mt = 0; mt < MF; ++mt) {
      int m = mrow + mt * 16 + rA;
      int w = m / 49, n = m - w * 49;
      int b = w >> 6, wrem = w & 63;
      int hi = wrem >> 3, wi = wrem & 7;
      int ii = n / 7, jj = n - ii * 7;
      int hs = hi * 7 + ii + 3; if (hs >= 56) hs -= 56;
      int wsc = wi * 7 + jj + 3; if (wsc >= 56) wsc -= 56;
      const float* rowp =
          (const float*)Ap + (size_t)((b * 56 + hs) * 56 + wsc) * CC;
      f32x4 xv[12];
#pragma unroll
      for (int kt = 0; kt < 6; ++kt) {
        xv[2 * kt]     = *(const f32x4*)(rowp + kt * 32 + grp * 8);
        xv[2 * kt + 1] = *(const f32x4*)(rowp + kt * 32 + grp * 8 + 4);
      }
      float s = 0.0f;
#pragma unroll
      for (int i = 0; i < 12; ++i)
#pragma unroll
        for (int j = 0; j < 4; ++j) s += xv[i][j];
      s += __shfl_xor(s, 16, 64);
      s += __shfl_xor(s, 32, 64);
      float mu = s * (1.0f / 192.0f);
      float q = 0.0f;
#pragma unroll
      for (int i = 0; i < 12; ++i)
#pragma unroll
        for (int j = 0; j < 4; ++j) {
          float d = xv[i][j] - mu;
          q += d * d;
        }
      q += __shfl_xor(q, 16, 64);
      q += __shfl_xor(q, 32, 64);
      float inv = rsqrtf(q * (1.0f / 192.0f) + 1e-5f);
#pragma unroll
      for (int kt = 0; kt < 6; ++kt) {
        short8 t;
#pragma unroll
        for (int j = 0; j < 8; ++j) {
          int col = kt * 32 + grp * 8 + j;
          float xval = xv[2 * kt + (j >> 2)][j & 3];
          float val = (xval - mu) * inv * lng[col] + lnb[col];
          bf16 hb = __float2bfloat16(val);
          t[j] = *reinterpret_cast<short*>(&hb);
        }
        areg[mt][kt] = t;
      }
    }
  }

  // ---- MODE 1: precompute scatter row offsets (n-independent) ----
  int rowoff[MF][4];
  if constexpr (MODE == 1) {
#pragma unroll
    for (int mt = 0; mt < MF; ++mt)
#pragma unroll
      for (int r = 0; r < 4; ++r) {
        int m = mrow + mt * 16 + cq * 4 + r;
        int w = m / 49, rr = m - w * 49;
        int b = w >> 6, wrem = w & 63;
        int hi = wrem >> 3, wi = wrem & 7;
        int ii = rr / 7, jj = rr - ii * 7;
        int hd = hi * 7 + ii + 3; if (hd >= 56) hd -= 56;
        int wd = wi * 7 + jj + 3; if (wd >= 56) wd -= 56;
        rowoff[mt][r] = ((b * 56 + hd) * 56 + wd) * CC;
      }
  }

  auto stage = [&](int buf, int nt, int kc) {
#pragma unroll
    for (int i = 0; i < 6; ++i) {
      int c = i * 256 + tid;                       // 16B chunk id, 24/row
      int row = c / 24;
      int cbl = ((c - row * 24) * 16) ^ ((row & 7) << 4);
      const char* src = (const char*)W +
          (size_t)(nt * 64 + row) * (K * 2) + kc * 384 + cbl;
      __builtin_amdgcn_global_load_lds(
          (const __attribute__((address_space(1))) void*)src,
          (__attribute__((address_space(3))) void*)((char*)&Bs[buf][0] + c * 16),
          16, 0, 0);
    }
  };
  stage(0, 0, 0);

  f32x4 acc[MF][4];
#pragma unroll
  for (int s = 0; s < NT * KC; ++s) {
    const int nt = s / KC, kc = s - nt * KC;
    const int cur = s & 1;
    __syncthreads();                          // drains cur's stage (vmcnt(0))
    if (s + 1 < NT * KC) stage(cur ^ 1, (s + 1) / KC, (s + 1) % KC);
    if (kc == 0) {
#pragma unroll
      for (int mt = 0; mt < MF; ++mt)
#pragma unroll
        for (int ntf = 0; ntf < 4; ++ntf)
          acc[mt][ntf] = (f32x4){0.f, 0.f, 0.f, 0.f};
    }
#pragma unroll
    for (int kt = 0; kt < 6; ++kt) {
      short8 b[4];
#pragma unroll
      for (int ntf = 0; ntf < 4; ++ntf) {
        int row = ntf * 16 + rA;
        int phys = row * 384 + ((kt * 64 + grp * 16) ^ ((row & 7) << 4));
        b[ntf] = *(const short8*)((const char*)&Bs[cur][0] + phys);
      }
#pragma unroll
      for (int mt = 0; mt < MF; ++mt)
#pragma unroll
        for (int ntf = 0; ntf < 4; ++ntf)
          acc[mt][ntf] = __builtin_amdgcn_mfma_f32_16x16x32_bf16(
              areg[mt][kc * 6 + kt], b[ntf], acc[mt][ntf], 0, 0, 0);
    }
    if (kc == KC - 1) {
      const int n0t = nt * 64;
      float bi[4];
#pragma unroll
      for (int ntf = 0; ntf < 4; ++ntf) bi[ntf] = bias[n0t + ntf * 16 + cn];
#pragma unroll
      for (int mt = 0; mt < MF; ++mt) {
#pragma unroll
        for (int r = 0; r < 4; ++r) {
          const int m = mrow + mt * 16 + cq * 4 + r;
#pragma unroll
          for (int ntf = 0; ntf < 4; ++ntf) {
            const int n = n0t + ntf * 16 + cn;
            float v = acc[mt][ntf][r] + bi[ntf];
            if constexpr (MODE == 0) {
              ((bf16*)out0)[(size_t)m * N + n] = __float2bfloat16(v);
            } else {
              float res = ((const float*)aux)[(size_t)rowoff[mt][r] + n];
              ((float*)out0)[(size_t)rowoff[mt][r] + n] = v + res;
            }
          }
        }
      }
    }
  }
}

// ---------------- fused MLP: out += GELU(LN2(x1) @ W1^T + b1) @ W2^T + b2 --
// Per wave: 32 rows (MF=2). Hidden never leaves the CU.
// W1 chunks double-buffer through Bs with ONE barrier per chunk (stage
// issued right after the barrier -> full-chunk prefetch window).
// W2 fragments are loaded global->VGPR (294 KB, L2-resident) -> no second
// stage, no second barrier.
__global__ __launch_bounds__(256, 2) void k_mlp(
    const float* __restrict__ x1, const bf16* __restrict__ W1,
    const bf16* __restrict__ W2, const float* __restrict__ b1,
    const float* __restrict__ b2, float* __restrict__ out,
    const float* __restrict__ lng, const float* __restrict__ lnb) {
  __shared__ bf16 Bs[2][64 * 192];   // W1 chunk double-buffer (2 x 24 KB)
  __shared__ bf16 Hl[4][32 * 72];    // per-wave hidden transpose tile
  const int tid = threadIdx.x;
  const int wave = tid >> 6, lane = tid & 63;
  const int grp = lane >> 4, rA = lane & 15;
  const int mrow = blockIdx.x * 128 + wave * 32;
  char* hb = (char*)&Hl[wave][0];

  // ---- LN2(x1) -> A fragments (row mt*16+rA, k = kt*32 + grp*8) ----
  short8 areg[2][6];
#pragma unroll
  for (int mt = 0; mt < 2; ++mt) {
    const float* rowp = x1 + (size_t)(mrow + mt * 16 + rA) * CC;
    f32x4 xv[12];
#pragma unroll
    for (int kt = 0; kt < 6; ++kt) {
      xv[2 * kt]     = *(const f32x4*)(rowp + kt * 32 + grp * 8);
      xv[2 * kt + 1] = *(const f32x4*)(rowp + kt * 32 + grp * 8 + 4);
    }
    float s = 0.0f;
#pragma unroll
    for (int i = 0; i < 12; ++i)
#pragma unroll
      for (int j = 0; j < 4; ++j) s += xv[i][j];
    s += __shfl_xor(s, 16, 64);
    s += __shfl_xor(s, 32, 64);
    float mu = s * (1.0f / 192.0f);
    float q = 0.0f;
#pragma unroll
    for (int i = 0; i < 12; ++i)
#pragma unroll
      for (int j = 0; j < 4; ++j) {
        float d = xv[i][j] - mu;
        q += d * d;
      }
    q += __shfl_xor(q, 16, 64);
    q += __shfl_xor(q, 32, 64);
    float inv = rsqrtf(q * (1.0f / 192.0f) + 1e-5f);
#pragma unroll
    for (int kt = 0; kt < 6; ++kt) {
      short8 t;
#pragma unroll
      for (int j = 0; j < 8; ++j) {
        int col = kt * 32 + grp * 8 + j;
        float xval = xv[2 * kt + (j >> 2)][j & 3];
        float val = (xval - mu) * inv * lng[col] + lnb[col];
        bf16 hbv = __float2bfloat16(val);
        t[j] = *reinterpret_cast<short*>(&hbv);
      }
      areg[mt][kt] = t;
    }
  }

  // W1 chunk c: rows c*64..c*64+64 of [768][192], row stride 384 B, 24 slots
  auto stage1 = [&](int buf, int c) {
#pragma unroll
    for (int i = 0; i < 6; ++i) {
      int cc = i * 256 + tid;
      int row = cc / 24;
      int cbl = ((cc - row * 24) * 16) ^ ((row & 7) << 4);
      const char* src = (const char*)W1 + (size_t)(c * 64 + row) * 384 + cbl;
      __builtin_amdgcn_global_load_lds(
          (const __attribute__((address_space(1))) void*)src,
          (__attribute__((address_space(3))) void*)((char*)&Bs[buf][0] + cc * 16),
          16, 0, 0);
    }
  };

  f32x4 acc2[2][12];
#pragma unroll
  for (int mt = 0; mt < 2; ++mt)
#pragma unroll
    for (int nf = 0; nf < 12; ++nf) acc2[mt][nf] = (f32x4){0.f, 0.f, 0.f, 0.f};

  stage1(0, 0);
  for (int c = 0; c < 12; ++c) {
    const int cur = c & 1;
    __syncthreads();                 // W1[c] landed (vmcnt(0)+lgkmcnt drain)
    if (c + 1 < 12) stage1(cur ^ 1, c + 1);  // flies under this whole chunk
    // ---- fc1 chunk: fa[mt][ntf] = A @ W1chunk^T ----
    f32x4 fa[2][4] = {};
#pragma unroll
    for (int kt = 0; kt < 6; ++kt) {
      short8 bfr[4];
#pragma unroll
      for (int ntf = 0; ntf < 4; ++ntf) {
        int row = ntf * 16 + rA;
        int phys = row * 384 + ((kt * 64 + grp * 16) ^ ((row & 7) << 4));
        bfr[ntf] = *(const short8*)((const char*)&Bs[cur][0] + phys);
      }
#pragma unroll
      for (int mt = 0; mt < 2; ++mt)
#pragma unroll
        for (int ntf = 0; ntf < 4; ++ntf)
          fa[mt][ntf] = __builtin_amdgcn_mfma_f32_16x16x32_bf16(
              areg[mt][kt], bfr[ntf], fa[mt][ntf], 0, 0, 0);
    }
    // ---- +b1, GELU (sigmoid form), write per-wave hidden tile ----
#pragma unroll
    for (int ntf = 0; ntf < 4; ++ntf) {
      float b1v = b1[c * 64 + ntf * 16 + rA];
#pragma unroll
      for (int mt = 0; mt < 2; ++mt) {
#pragma unroll
        for (int r = 0; r < 4; ++r) {
          float v = fa[mt][ntf][r] + b1v;
          float u2 = 2.0f * v * (0.7978845608f + 0.0356774081f * v * v);
          float ge = v / (1.0f + __expf(-u2));
          int row = mt * 16 + grp * 4 + r;
          int byte = (row * 144 + (ntf * 16 + rA) * 2) ^ ((row & 8) << 1);
          *(bf16*)(hb + byte) = __float2bfloat16(ge);
        }
      }
    }
    // ---- fc2 accumulate: acc2 += h_chunk @ W2chunk^T (W2 from L2) ----
    short8 a2[2][2];
#pragma unroll
    for (int mt = 0; mt < 2; ++mt)
#pragma unroll
      for (int kt2 = 0; kt2 < 2; ++kt2)
        a2[mt][kt2] = *(const short8*)(
            hb + (((mt * 16 + rA) * 144 + grp * 16 + kt2 * 64) ^ ((rA & 8) << 1)));
#pragma unroll
    for (int nf = 0; nf < 12; ++nf) {
      const bf16* wrow = W2 + (size_t)(nf * 16 + rA) * HIDDEN + c * 64 + grp * 8;
      short8 bw0 = *(const short8*)(wrow);
      short8 bw1 = *(const short8*)(wrow + 32);
#pragma unroll
      for (int mt = 0; mt < 2; ++mt) {
        acc2[mt][nf] = __builtin_amdgcn_mfma_f32_16x16x32_bf16(
            a2[mt][0], bw0, acc2[mt][nf], 0, 0, 0);
        acc2[mt][nf] = __builtin_amdgcn_mfma_f32_16x16x32_bf16(
            a2[mt][1], bw1, acc2[mt][nf], 0, 0, 0);
      }
    }
  }

  // ---- epilogue: out[m,n] += acc2 + b2 (residual RMW; out == x1) ----
#pragma unroll
  for (int nf = 0; nf < 12; ++nf) {
    float b2v = b2[nf * 16 + rA];
#pragma unroll
    for (int mt = 0; mt < 2; ++mt) {
#pragma unroll
      for (int r = 0; r < 4; ++r) {
        int m = mrow + mt * 16 + grp * 4 + r;
        size_t idx = (size_t)m * CC + nf * 16 + rA;
        out[idx] = out[idx] + acc2[mt][nf][r] + b2v;
      }
    }
  }
}

// ---------------- MFMA attention: 1 wave per (window,head) ---------------
__global__ __launch_bounds__(256) void k_attn_mfma(
    const bf16* __restrict__ qk, const float* __restrict__ bias6,
    bf16* __restrict__ ao) {
  __shared__ bf16 P[4][64 * 72];
  __shared__ bf16 VT[4][32 * 72];
  const int wave = threadIdx.x >> 6, lane = threadIdx.x & 63;
  const int wh = blockIdx.x * 4 + wave;
  const int w = wh / NHEADS, h = wh - w * NHEADS;
  const int rA = lane & 15, kq = (lane >> 4) * 8;
  const int grp = lane >> 4;

  const bf16* qbase = qk + (size_t)(w * 49) * 576 + h * HDIM + kq;

  short8 aq[4], bk[4], vrow[4];
#pragma unroll
  for (int t = 0; t < 4; ++t) {
    const bf16* rp = qbase + (size_t)(t * 16 + rA) * 576;
    aq[t] = *(const short8*)(rp);
    bk[t] = *(const short8*)(rp + 192);
    vrow[t] = *(const short8*)(rp + 384);
  }

  f32x4 S[4][4] = {};
#pragma unroll
  for (int mt = 0; mt < 4; ++mt)
#pragma unroll
    for (int nt = 0; nt < 4; ++nt)
      S[mt][nt] = __builtin_amdgcn_mfma_f32_16x16x32_bf16(
          aq[mt], bk[nt], S[mt][nt], 0, 0, 0);

  bf16* Vw = VT[wave];
  const bf16 zero = __float2bfloat16(0.0f);
#pragma unroll
  for (int t = 0; t < 4; ++t) {
    int tok = t * 16 + rA;
#pragma unroll
    for (int j = 0; j < 8; ++j)
      Vw[(kq + j) * 72 + tok] = (tok < 49) ? ((const bf16*)&vrow[t])[j] : zero;
  }

  const float scale = 0.17677669529663687f;
  const float* bh = bias6 + h * 2401;
  float rs[4][4];
  bf16* Pw = P[wave];
#pragma unroll
  for (int mt = 0; mt < 4; ++mt) {
#pragma unroll
    for (int r = 0; r < 4; ++r) {
      int row = mt * 16 + grp * 4 + r;
      float val[4];
#pragma unroll
      for (int nt = 0; nt < 4; ++nt) {
        int c = nt * 16 + rA;
        float bv = (row < 49 && c < 49) ? bh[row * 49 + c] : 0.0f;
        val[nt] = (c < 49) ? (S[mt][nt][r] * scale + bv) : -1e30f;
      }
      float mx = fmaxf(fmaxf(val[0], val[1]), fmaxf(val[2], val[3]));
      for (int m2 = 1; m2 < 16; m2 <<= 1) mx = fmaxf(mx, __shfl_xor(mx, m2, 64));
      float sum = 0.0f;
#pragma unroll
      for (int nt = 0; nt < 4; ++nt) {
        float e = __expf(val[nt] - mx);
        val[nt] = e;
        sum += e;
      }
      for (int m2 = 1; m2 < 16; m2 <<= 1) sum += __shfl_xor(sum, m2, 64);
      rs[mt][r] = 1.0f / sum;
#pragma unroll
      for (int nt = 0; nt < 4; ++nt)
        Pw[row * 72 + nt * 16 + rA] = __float2bfloat16(val[nt]);
    }
  }
  __syncthreads();

  short8 bv[2][2];
#pragma unroll
  for (int ks = 0; ks < 2; ++ks)
#pragma unroll
    for (int nt = 0; nt < 2; ++nt)
      bv[ks][nt] = *(const short8*)&Vw[(nt * 16 + rA) * 72 + ks * 32 + kq];
  f32x4 O[4][2] = {};
#pragma unroll
  for (int mt = 0; mt < 4; ++mt) {
    short8 ap0 = *(const short8*)&Pw[(mt * 16 + rA) * 72 + kq];
    short8 ap1 = *(const short8*)&Pw[(mt * 16 + rA) * 72 + 32 + kq];
#pragma unroll
    for (int nt = 0; nt < 2; ++nt) {
      O[mt][nt] = __builtin_amdgcn_mfma_f32_16x16x32_bf16(ap0, bv[0][nt],
                                                          O[mt][nt], 0, 0, 0);
      O[mt][nt] = __builtin_amdgcn_mfma_f32_16x16x32_bf16(ap1, bv[1][nt],
                                                          O[mt][nt], 0, 0, 0);
    }
  }
#pragma unroll
  for (int mt = 0; mt < 4; ++mt) {
#pragma unroll
    for (int r = 0; r < 4; ++r) {
      int m = mt * 16 + grp * 4 + r;
      if (m < 49) {
        bf16* orow = ao + (size_t)(w * 49 + m) * CC + h * HDIM;
#pragma unroll
        for (int nt = 0; nt < 2; ++nt)
          orow[nt * 16 + rA] = __float2bfloat16(O[mt][nt][r] * rs[mt][r]);
      }
    }
  }
}

// ---------------- launcher ----------------
extern "C" void kernel_launch(void* const* d_in, const int* in_sizes, int n_in,
                              void* d_out, int out_size, void* d_ws, size_t ws_size,
                              hipStream_t stream) {
  const float* x        = (const float*)d_in[0];
  const float* norm1_g  = (const float*)d_in[1];
  const float* norm1_b  = (const float*)d_in[2];
  const float* qkv_w    = (const float*)d_in[3];
  const float* qkv_b    = (const float*)d_in[4];
  const float* proj_w   = (const float*)d_in[5];
  const float* proj_b   = (const float*)d_in[6];
  const float* rel_tab  = (const float*)d_in[7];
  const float* norm2_g  = (const float*)d_in[8];
  const float* norm2_b  = (const float*)d_in[9];
  const float* fc1_w    = (const float*)d_in[10];
  const float* fc1_b    = (const float*)d_in[11];
  const float* fc2_w    = (const float*)d_in[12];
  const float* fc2_b    = (const float*)d_in[13];
  const int*   rel_idx  = (const int*)d_in[14];
  float* out = (float*)d_out;

  // workspace layout (bytes):
  //   [0,          115,605,504)  qkb [M,576] bf16
  //   [115,605,504,154,140,672)  ao  [M,192] bf16
  //   [154,140,672,155,025,408)  wbuf bf16 weights
  //   [155,025,408,155,083,032)  bias6 fp32
  char* ws = (char*)d_ws;
  bf16*  qkb   = (bf16*)ws;
  bf16*  ao    = (bf16*)(ws + 115605504);
  bf16*  wbuf  = (bf16*)(ws + 154140672);
  float* bias6 = (float*)(ws + 155025408);
  float* x1    = out;   // fp32 residual trunk lives in d_out
  bf16* wq = wbuf;
  bf16* wp = wbuf + 110592;
  bf16* w1 = wbuf + 147456;
  bf16* w2 = wbuf + 294912;

  k_wconv<<<1728, 256, 0, stream>>>(qkv_w, proj_w, fc1_w, fc2_w, wbuf);
  k_bias<<<57, 256, 0, stream>>>(rel_tab, rel_idx, bias6);
  // qkv with fused LN1 + roll/partition: x fp32 -> qkb [M,576] bf16
  k_gemm_areg<0, 9, 1, 1><<<MTOK / 64, 256, 0, stream>>>(
      x, wq, qkv_b, qkb, nullptr, norm1_g, norm1_b);
  k_attn_mfma<<<NWIN * NHEADS / 4, 256, 0, stream>>>(qkb, bias6, ao);
  // proj + reverse/roll + residual -> x1 (d_out, fp32 natural order)
  k_gemm_areg<1, 3, 1, 2><<<MTOK / 128, 256, 0, stream>>>(
      ao, wp, proj_b, x1, x, nullptr, nullptr);
  // fused MLP: out += GELU(LN2(x1) @ W1^T + b1) @ W2^T + b2
  k_mlp<<<MTOK / 128, 256, 0, stream>>>(
      x1, w1, w2, fc1_b, fc2_b, out, norm2_g, norm2_b);
}

// Round 5
// 463.442 us; speedup vs baseline: 1.2386x; 1.2386x over previous
//
#include <hip/hip_runtime.h>
#include <hip/hip_bf16.h>

// ---------------- problem constants ----------------
#define CC 192
#define NHEADS 6
#define HDIM 32
#define NTOK 49
#define NWIN 2048
#define MTOK 100352      // NWIN * NTOK
#define HIDDEN 768

typedef __hip_bfloat16 bf16;
typedef __attribute__((ext_vector_type(8))) short short8;
typedef __attribute__((ext_vector_type(4))) float f32x4;

// ---------------- weight fp32 -> bf16 conversion ----------------
__global__ __launch_bounds__(256) void k_wconv(
    const float* __restrict__ qw, const float* __restrict__ pw,
    const float* __restrict__ f1, const float* __restrict__ f2,
    bf16* __restrict__ o) {
  int i = blockIdx.x * 256 + threadIdx.x;
  if (i < 110592) o[i] = __float2bfloat16(qw[i]);
  else if (i < 147456) o[i] = __float2bfloat16(pw[i - 110592]);
  else if (i < 294912) o[i] = __float2bfloat16(f1[i - 147456]);
  else if (i < 442368) o[i] = __float2bfloat16(f2[i - 294912]);
}

// ---------------- bias6[h][49][49] = table[ridx[r*49+c]*6+h] -------------
__global__ __launch_bounds__(256) void k_bias(
    const float* __restrict__ table, const int* __restrict__ ridx,
    float* __restrict__ bias6) {
  int i = blockIdx.x * 256 + threadIdx.x;
  if (i >= 6 * 2401) return;
  int h = i / 2401, e = i - h * 2401;
  bias6[i] = table[ridx[e] * NHEADS + h];
}

// ---------------- A-register-resident MFMA GEMM ----------------
// MODE 0: A = x fp32, fused LN1 + roll(-3,-3) + window partition; bf16 out
// MODE 1: A = ao bf16; proj + window-reverse/roll + residual (fp32 scatter)
template <int MODE, int NT, int KC, int MF>
__global__ __launch_bounds__(256) void k_gemm_areg(
    const void* __restrict__ Ap, const bf16* __restrict__ W,
    const float* __restrict__ bias, void* __restrict__ out0,
    const void* __restrict__ aux, const float* __restrict__ lng,
    const float* __restrict__ lnb) {
  constexpr int K = KC * 192;
  constexpr int N = NT * 64;
  __shared__ bf16 Bs[2][64 * 192];   // 2 x 24 KB
  const int tid = threadIdx.x;
  const int wave = tid >> 6, lane = tid & 63;
  const int grp = lane >> 4, rA = lane & 15;
  const int cq = grp, cn = rA;
  const int m0 = blockIdx.x * (MF * 64);
  const int mrow = m0 + wave * (MF * 16);

  // ---- A fragments: global -> regs, exactly once ----
  short8 areg[MF][KC * 6];
  if constexpr (MODE == 1) {
#pragma unroll
    for (int mt = 0; mt < MF; ++mt) {
      const bf16* arow =
          (const bf16*)Ap + (size_t)(mrow + mt * 16 + rA) * K + grp * 8;
#pragma unroll
      for (int kt = 0; kt < KC * 6; ++kt)
        areg[mt][kt] = *(const short8*)(arow + kt * 32);
    }
  } else {
    // fp32 input + fused LayerNorm + roll/partition (K == 192).
#pragma unroll
    for (int mt = 0; mt < MF; ++mt) {
      int m = mrow + mt * 16 + rA;
      int w = m / 49, n = m - w * 49;
      int b = w >> 6, wrem = w & 63;
      int hi = wrem >> 3, wi = wrem & 7;
      int ii = n / 7, jj = n - ii * 7;
      int hs = hi * 7 + ii + 3; if (hs >= 56) hs -= 56;
      int wsc = wi * 7 + jj + 3; if (wsc >= 56) wsc -= 56;
      const float* rowp =
          (const float*)Ap + (size_t)((b * 56 + hs) * 56 + wsc) * CC;
      f32x4 xv[12];
#pragma unroll
      for (int kt = 0; kt < 6; ++kt) {
        xv[2 * kt]     = *(const f32x4*)(rowp + kt * 32 + grp * 8);
        xv[2 * kt + 1] = *(const f32x4*)(rowp + kt * 32 + grp * 8 + 4);
      }
      float s = 0.0f;
#pragma unroll
      for (int i = 0; i < 12; ++i)
#pragma unroll
        for (int j = 0; j < 4; ++j) s += xv[i][j];
      s += __shfl_xor(s, 16, 64);
      s += __shfl_xor(s, 32, 64);
      float mu = s * (1.0f / 192.0f);
      float q = 0.0f;
#pragma unroll
      for (int i = 0; i < 12; ++i)
#pragma unroll
        for (int j = 0; j < 4; ++j) {
          float d = xv[i][j] - mu;
          q += d * d;
        }
      q += __shfl_xor(q, 16, 64);
      q += __shfl_xor(q, 32, 64);
      float inv = rsqrtf(q * (1.0f / 192.0f) + 1e-5f);
#pragma unroll
      for (int kt = 0; kt < 6; ++kt) {
        short8 t;
#pragma unroll
        for (int j = 0; j < 8; ++j) {
          int col = kt * 32 + grp * 8 + j;
          float xval = xv[2 * kt + (j >> 2)][j & 3];
          float val = (xval - mu) * inv * lng[col] + lnb[col];
          bf16 hb = __float2bfloat16(val);
          t[j] = *reinterpret_cast<short*>(&hb);
        }
        areg[mt][kt] = t;
      }
    }
  }

  // ---- MODE 1: precompute scatter row offsets (n-independent) ----
  int rowoff[MF][4];
  if constexpr (MODE == 1) {
#pragma unroll
    for (int mt = 0; mt < MF; ++mt)
#pragma unroll
      for (int r = 0; r < 4; ++r) {
        int m = mrow + mt * 16 + cq * 4 + r;
        int w = m / 49, rr = m - w * 49;
        int b = w >> 6, wrem = w & 63;
        int hi = wrem >> 3, wi = wrem & 7;
        int ii = rr / 7, jj = rr - ii * 7;
        int hd = hi * 7 + ii + 3; if (hd >= 56) hd -= 56;
        int wd = wi * 7 + jj + 3; if (wd >= 56) wd -= 56;
        rowoff[mt][r] = ((b * 56 + hd) * 56 + wd) * CC;
      }
  }

  auto stage = [&](int buf, int nt, int kc) {
#pragma unroll
    for (int i = 0; i < 6; ++i) {
      int c = i * 256 + tid;                       // 16B chunk id, 24/row
      int row = c / 24;
      int cbl = ((c - row * 24) * 16) ^ ((row & 7) << 4);
      const char* src = (const char*)W +
          (size_t)(nt * 64 + row) * (K * 2) + kc * 384 + cbl;
      __builtin_amdgcn_global_load_lds(
          (const __attribute__((address_space(1))) void*)src,
          (__attribute__((address_space(3))) void*)((char*)&Bs[buf][0] + c * 16),
          16, 0, 0);
    }
  };
  stage(0, 0, 0);

  f32x4 acc[MF][4];
#pragma unroll
  for (int s = 0; s < NT * KC; ++s) {
    const int nt = s / KC, kc = s - nt * KC;
    const int cur = s & 1;
    __syncthreads();                          // drains cur's stage (vmcnt(0))
    if (s + 1 < NT * KC) stage(cur ^ 1, (s + 1) / KC, (s + 1) % KC);
    if (kc == 0) {
#pragma unroll
      for (int mt = 0; mt < MF; ++mt)
#pragma unroll
        for (int ntf = 0; ntf < 4; ++ntf)
          acc[mt][ntf] = (f32x4){0.f, 0.f, 0.f, 0.f};
    }
#pragma unroll
    for (int kt = 0; kt < 6; ++kt) {
      short8 b[4];
#pragma unroll
      for (int ntf = 0; ntf < 4; ++ntf) {
        int row = ntf * 16 + rA;
        int phys = row * 384 + ((kt * 64 + grp * 16) ^ ((row & 7) << 4));
        b[ntf] = *(const short8*)((const char*)&Bs[cur][0] + phys);
      }
#pragma unroll
      for (int mt = 0; mt < MF; ++mt)
#pragma unroll
        for (int ntf = 0; ntf < 4; ++ntf)
          acc[mt][ntf] = __builtin_amdgcn_mfma_f32_16x16x32_bf16(
              areg[mt][kc * 6 + kt], b[ntf], acc[mt][ntf], 0, 0, 0);
    }
    if (kc == KC - 1) {
      const int n0t = nt * 64;
      float bi[4];
#pragma unroll
      for (int ntf = 0; ntf < 4; ++ntf) bi[ntf] = bias[n0t + ntf * 16 + cn];
#pragma unroll
      for (int mt = 0; mt < MF; ++mt) {
#pragma unroll
        for (int r = 0; r < 4; ++r) {
          const int m = mrow + mt * 16 + cq * 4 + r;
#pragma unroll
          for (int ntf = 0; ntf < 4; ++ntf) {
            const int n = n0t + ntf * 16 + cn;
            float v = acc[mt][ntf][r] + bi[ntf];
            if constexpr (MODE == 0) {
              ((bf16*)out0)[(size_t)m * N + n] = __float2bfloat16(v);
            } else {
              float res = ((const float*)aux)[(size_t)rowoff[mt][r] + n];
              ((float*)out0)[(size_t)rowoff[mt][r] + n] = v + res;
            }
          }
        }
      }
    }
  }
}

// ---------------- fused MLP: out += GELU(LN2(x1) @ W1^T + b1) @ W2^T + b2 --
// Per wave: 16 rows (MF=1). Hidden never leaves the CU.
// CH=32 hidden-chunk; W1 AND W2 chunks double-buffered (2x12 KB each) with
// ONE barrier per chunk -> stage window = full chunk body.
// LDS = 54.3 KB -> 3 blocks/CU (12 waves/CU).
__global__ __launch_bounds__(256) void k_mlp(
    const float* __restrict__ x1, const bf16* __restrict__ W1,
    const bf16* __restrict__ W2, const float* __restrict__ b1,
    const float* __restrict__ b2, float* __restrict__ out,
    const float* __restrict__ lng, const float* __restrict__ lnb) {
  __shared__ bf16 W1s[2][32 * 192];   // 2 x 12 KB  [32 hidden][192 k]
  __shared__ bf16 W2s[2][192 * 32];   // 2 x 12 KB  [192 out][32 hidden]
  __shared__ bf16 Hl[4][640];         // per-wave 16 x 32 hidden, 80 B row
  const int tid = threadIdx.x;
  const int wave = tid >> 6, lane = tid & 63;
  const int grp = lane >> 4, rA = lane & 15;
  const int mrow = blockIdx.x * 64 + wave * 16;
  char* hb = (char*)&Hl[wave][0];

  // ---- LN2(x1) -> A fragments (row rA, k = kt*32 + grp*8) ----
  short8 areg[6];
  {
    const float* rowp = x1 + (size_t)(mrow + rA) * CC;
    f32x4 xv[12];
#pragma unroll
    for (int kt = 0; kt < 6; ++kt) {
      xv[2 * kt]     = *(const f32x4*)(rowp + kt * 32 + grp * 8);
      xv[2 * kt + 1] = *(const f32x4*)(rowp + kt * 32 + grp * 8 + 4);
    }
    float s = 0.0f;
#pragma unroll
    for (int i = 0; i < 12; ++i)
#pragma unroll
      for (int j = 0; j < 4; ++j) s += xv[i][j];
    s += __shfl_xor(s, 16, 64);
    s += __shfl_xor(s, 32, 64);
    float mu = s * (1.0f / 192.0f);
    float q = 0.0f;
#pragma unroll
    for (int i = 0; i < 12; ++i)
#pragma unroll
      for (int j = 0; j < 4; ++j) {
        float d = xv[i][j] - mu;
        q += d * d;
      }
    q += __shfl_xor(q, 16, 64);
    q += __shfl_xor(q, 32, 64);
    float inv = rsqrtf(q * (1.0f / 192.0f) + 1e-5f);
#pragma unroll
    for (int kt = 0; kt < 6; ++kt) {
      short8 t;
#pragma unroll
      for (int j = 0; j < 8; ++j) {
        int col = kt * 32 + grp * 8 + j;
        float xval = xv[2 * kt + (j >> 2)][j & 3];
        float val = (xval - mu) * inv * lng[col] + lnb[col];
        bf16 hbv = __float2bfloat16(val);
        t[j] = *reinterpret_cast<short*>(&hbv);
      }
      areg[kt] = t;
    }
  }

  // W1 chunk c: hidden rows c*32..+32 of [768][192]; 768 16B slots, 24/row.
  auto stage1 = [&](int buf, int c) {
#pragma unroll
    for (int i = 0; i < 3; ++i) {
      int s = i * 256 + tid;
      int row = s / 24, slot = s - row * 24;
      int cbl = (slot * 16) ^ ((row & 7) << 4);
      const char* src = (const char*)W1 + (size_t)(c * 32 + row) * 384 + cbl;
      __builtin_amdgcn_global_load_lds(
          (const __attribute__((address_space(1))) void*)src,
          (__attribute__((address_space(3))) void*)((char*)&W1s[buf][0] + s * 16),
          16, 0, 0);
    }
  };
  // W2 chunk c: hidden cols c*32..+32 of [192][768]; 768 16B slots, 4/row.
  auto stage2 = [&](int buf, int c) {
#pragma unroll
    for (int i = 0; i < 3; ++i) {
      int s = i * 256 + tid;
      int row = s >> 2, slot = s & 3;
      int cbl = (slot * 16) ^ (((row >> 1) & 3) << 4);
      const char* src = (const char*)W2 + (size_t)row * 1536 + c * 64 + cbl;
      __builtin_amdgcn_global_load_lds(
          (const __attribute__((address_space(1))) void*)src,
          (__attribute__((address_space(3))) void*)((char*)&W2s[buf][0] + s * 16),
          16, 0, 0);
    }
  };

  f32x4 acc2[12];
#pragma unroll
  for (int nf = 0; nf < 12; ++nf) acc2[nf] = (f32x4){0.f, 0.f, 0.f, 0.f};

  stage1(0, 0);
  stage2(0, 0);
  for (int c = 0; c < 24; ++c) {
    const int cur = c & 1;
    __syncthreads();                 // chunk c's stages landed; buf^1 free
    if (c + 1 < 24) { stage1(cur ^ 1, c + 1); stage2(cur ^ 1, c + 1); }
    // ---- fc1 chunk: fa[ntf] = A @ W1chunk^T  (ntf = 2 x 16 hidden) ----
    f32x4 fa[2] = {};
#pragma unroll
    for (int kt = 0; kt < 6; ++kt) {
      short8 bfr[2];
#pragma unroll
      for (int ntf = 0; ntf < 2; ++ntf) {
        int row = ntf * 16 + rA;
        int phys = row * 384 + ((kt * 64 + grp * 16) ^ ((row & 7) << 4));
        bfr[ntf] = *(const short8*)((const char*)&W1s[cur][0] + phys);
      }
#pragma unroll
      for (int ntf = 0; ntf < 2; ++ntf)
        fa[ntf] = __builtin_amdgcn_mfma_f32_16x16x32_bf16(
            areg[kt], bfr[ntf], fa[ntf], 0, 0, 0);
    }
    // ---- +b1, GELU (sigmoid form), write per-wave hidden tile ----
#pragma unroll
    for (int ntf = 0; ntf < 2; ++ntf) {
      float b1v = b1[c * 32 + ntf * 16 + rA];
#pragma unroll
      for (int r = 0; r < 4; ++r) {
        float v = fa[ntf][r] + b1v;
        float u2 = 2.0f * v * (0.7978845608f + 0.0356774081f * v * v);
        float ge = v / (1.0f + __expf(-u2));
        int row = grp * 4 + r;
        *(bf16*)(hb + row * 80 + (ntf * 16 + rA) * 2) = __float2bfloat16(ge);
      }
    }
    // ---- fc2 accumulate: acc2 += h_chunk @ W2chunk^T (one K=32 step) ----
    short8 a2 = *(const short8*)(hb + rA * 80 + grp * 16);
#pragma unroll
    for (int nf = 0; nf < 12; ++nf) {
      int row = nf * 16 + rA;
      int phys = row * 64 + ((grp * 16) ^ (((row >> 1) & 3) << 4));
      short8 bw = *(const short8*)((const char*)&W2s[cur][0] + phys);
      acc2[nf] = __builtin_amdgcn_mfma_f32_16x16x32_bf16(a2, bw, acc2[nf],
                                                         0, 0, 0);
    }
  }

  // ---- epilogue: out[m,n] += acc2 + b2 (residual RMW; out == x1) ----
#pragma unroll
  for (int nf = 0; nf < 12; ++nf) {
    float b2v = b2[nf * 16 + rA];
#pragma unroll
    for (int r = 0; r < 4; ++r) {
      int m = mrow + grp * 4 + r;
      size_t idx = (size_t)m * CC + nf * 16 + rA;
      out[idx] = out[idx] + acc2[nf][r] + b2v;
    }
  }
}

// ---------------- MFMA attention: 1 wave per (window,head) ---------------
__global__ __launch_bounds__(256) void k_attn_mfma(
    const bf16* __restrict__ qk, const float* __restrict__ bias6,
    bf16* __restrict__ ao) {
  __shared__ bf16 P[4][64 * 72];
  __shared__ bf16 VT[4][32 * 72];
  const int wave = threadIdx.x >> 6, lane = threadIdx.x & 63;
  const int wh = blockIdx.x * 4 + wave;
  const int w = wh / NHEADS, h = wh - w * NHEADS;
  const int rA = lane & 15, kq = (lane >> 4) * 8;
  const int grp = lane >> 4;

  const bf16* qbase = qk + (size_t)(w * 49) * 576 + h * HDIM + kq;

  short8 aq[4], bk[4], vrow[4];
#pragma unroll
  for (int t = 0; t < 4; ++t) {
    const bf16* rp = qbase + (size_t)(t * 16 + rA) * 576;
    aq[t] = *(const short8*)(rp);
    bk[t] = *(const short8*)(rp + 192);
    vrow[t] = *(const short8*)(rp + 384);
  }

  f32x4 S[4][4] = {};
#pragma unroll
  for (int mt = 0; mt < 4; ++mt)
#pragma unroll
    for (int nt = 0; nt < 4; ++nt)
      S[mt][nt] = __builtin_amdgcn_mfma_f32_16x16x32_bf16(
          aq[mt], bk[nt], S[mt][nt], 0, 0, 0);

  bf16* Vw = VT[wave];
  const bf16 zero = __float2bfloat16(0.0f);
#pragma unroll
  for (int t = 0; t < 4; ++t) {
    int tok = t * 16 + rA;
#pragma unroll
    for (int j = 0; j < 8; ++j)
      Vw[(kq + j) * 72 + tok] = (tok < 49) ? ((const bf16*)&vrow[t])[j] : zero;
  }

  const float scale = 0.17677669529663687f;
  const float* bh = bias6 + h * 2401;
  float rs[4][4];
  bf16* Pw = P[wave];
#pragma unroll
  for (int mt = 0; mt < 4; ++mt) {
#pragma unroll
    for (int r = 0; r < 4; ++r) {
      int row = mt * 16 + grp * 4 + r;
      float val[4];
#pragma unroll
      for (int nt = 0; nt < 4; ++nt) {
        int c = nt * 16 + rA;
        float bv = (row < 49 && c < 49) ? bh[row * 49 + c] : 0.0f;
        val[nt] = (c < 49) ? (S[mt][nt][r] * scale + bv) : -1e30f;
      }
      float mx = fmaxf(fmaxf(val[0], val[1]), fmaxf(val[2], val[3]));
      for (int m2 = 1; m2 < 16; m2 <<= 1) mx = fmaxf(mx, __shfl_xor(mx, m2, 64));
      float sum = 0.0f;
#pragma unroll
      for (int nt = 0; nt < 4; ++nt) {
        float e = __expf(val[nt] - mx);
        val[nt] = e;
        sum += e;
      }
      for (int m2 = 1; m2 < 16; m2 <<= 1) sum += __shfl_xor(sum, m2, 64);
      rs[mt][r] = 1.0f / sum;
#pragma unroll
      for (int nt = 0; nt < 4; ++nt)
        Pw[row * 72 + nt * 16 + rA] = __float2bfloat16(val[nt]);
    }
  }
  __syncthreads();

  short8 bv[2][2];
#pragma unroll
  for (int ks = 0; ks < 2; ++ks)
#pragma unroll
    for (int nt = 0; nt < 2; ++nt)
      bv[ks][nt] = *(const short8*)&Vw[(nt * 16 + rA) * 72 + ks * 32 + kq];
  f32x4 O[4][2] = {};
#pragma unroll
  for (int mt = 0; mt < 4; ++mt) {
    short8 ap0 = *(const short8*)&Pw[(mt * 16 + rA) * 72 + kq];
    short8 ap1 = *(const short8*)&Pw[(mt * 16 + rA) * 72 + 32 + kq];
#pragma unroll
    for (int nt = 0; nt < 2; ++nt) {
      O[mt][nt] = __builtin_amdgcn_mfma_f32_16x16x32_bf16(ap0, bv[0][nt],
                                                          O[mt][nt], 0, 0, 0);
      O[mt][nt] = __builtin_amdgcn_mfma_f32_16x16x32_bf16(ap1, bv[1][nt],
                                                          O[mt][nt], 0, 0, 0);
    }
  }
#pragma unroll
  for (int mt = 0; mt < 4; ++mt) {
#pragma unroll
    for (int r = 0; r < 4; ++r) {
      int m = mt * 16 + grp * 4 + r;
      if (m < 49) {
        bf16* orow = ao + (size_t)(w * 49 + m) * CC + h * HDIM;
#pragma unroll
        for (int nt = 0; nt < 2; ++nt)
          orow[nt * 16 + rA] = __float2bfloat16(O[mt][nt][r] * rs[mt][r]);
      }
    }
  }
}

// ---------------- launcher ----------------
extern "C" void kernel_launch(void* const* d_in, const int* in_sizes, int n_in,
                              void* d_out, int out_size, void* d_ws, size_t ws_size,
                              hipStream_t stream) {
  const float* x        = (const float*)d_in[0];
  const float* norm1_g  = (const float*)d_in[1];
  const float* norm1_b  = (const float*)d_in[2];
  const float* qkv_w    = (const float*)d_in[3];
  const float* qkv_b    = (const float*)d_in[4];
  const float* proj_w   = (const float*)d_in[5];
  const float* proj_b   = (const float*)d_in[6];
  const float* rel_tab  = (const float*)d_in[7];
  const float* norm2_g  = (const float*)d_in[8];
  const float* norm2_b  = (const float*)d_in[9];
  const float* fc1_w    = (const float*)d_in[10];
  const float* fc1_b    = (const float*)d_in[11];
  const float* fc2_w    = (const float*)d_in[12];
  const float* fc2_b    = (const float*)d_in[13];
  const int*   rel_idx  = (const int*)d_in[14];
  float* out = (float*)d_out;

  // workspace layout (bytes):
  //   [0,          115,605,504)  qkb [M,576] bf16
  //   [115,605,504,154,140,672)  ao  [M,192] bf16
  //   [154,140,672,155,025,408)  wbuf bf16 weights
  //   [155,025,408,155,083,032)  bias6 fp32
  char* ws = (char*)d_ws;
  bf16*  qkb   = (bf16*)ws;
  bf16*  ao    = (bf16*)(ws + 115605504);
  bf16*  wbuf  = (bf16*)(ws + 154140672);
  float* bias6 = (float*)(ws + 155025408);
  float* x1    = out;   // fp32 residual trunk lives in d_out
  bf16* wq = wbuf;
  bf16* wp = wbuf + 110592;
  bf16* w1 = wbuf + 147456;
  bf16* w2 = wbuf + 294912;

  k_wconv<<<1728, 256, 0, stream>>>(qkv_w, proj_w, fc1_w, fc2_w, wbuf);
  k_bias<<<57, 256, 0, stream>>>(rel_tab, rel_idx, bias6);
  // qkv with fused LN1 + roll/partition: x fp32 -> qkb [M,576] bf16
  k_gemm_areg<0, 9, 1, 1><<<MTOK / 64, 256, 0, stream>>>(
      x, wq, qkv_b, qkb, nullptr, norm1_g, norm1_b);
  k_attn_mfma<<<NWIN * NHEADS / 4, 256, 0, stream>>>(qkb, bias6, ao);
  // proj + reverse/roll + residual -> x1 (d_out, fp32 natural order)
  k_gemm_areg<1, 3, 1, 2><<<MTOK / 128, 256, 0, stream>>>(
      ao, wp, proj_b, x1, x, nullptr, nullptr);
  // fused MLP: out += GELU(LN2(x1) @ W1^T + b1) @ W2^T + b2
  k_mlp<<<MTOK / 64, 256, 0, stream>>>(
      x1, w1, w2, fc1_b, fc2_b, out, norm2_g, norm2_b);
}